// Round 4
// baseline (53.773 us; speedup 1.0000x reference)
//
#include <hip/hip_runtime.h>
#include <hip/hip_fp16.h>

#define SIGMA_F   1e-4f
#define GAMMA_F   1e-4f
#define ZNEAR_F   1.0f
#define ZFAR_F    100.0f
#define EPS_F     1e-10f

// Cull threshold: w = prob * exp((zinv - zmax)/GAMMA). exp(-60) ~ 8.8e-27,
// and denom >= delta >= 1e-10, so dropped terms are invisible at f32.
#define CULL_ARG  (-60.0f)

// Clang vector types: __builtin_nontemporal_load/store require real vector
// types, not HIP_vector_type structs.
typedef float f32x4 __attribute__((ext_vector_type(4)));
typedef int   i32x4 __attribute__((ext_vector_type(4)));

// ---------------------------------------------------------------------------
// Kernel A: materialize per-face vertex normals as f16, padded to 32 B/face.
// attrs[f] = { n0x n0y n0z n1x n1y n1z n2x n2y n2z, 7 x pad } (16 halves)
// ---------------------------------------------------------------------------
struct __align__(16) H16 { __half h[16]; };

__global__ __launch_bounds__(256) void build_face_attrs(
    const int*   __restrict__ faces,
    const float* __restrict__ vnorm,
    H16*         __restrict__ attrs,
    int F)
{
    int f = blockIdx.x * blockDim.x + threadIdx.x;
    if (f >= F) return;
    int v0 = faces[(size_t)f * 3 + 0];
    int v1 = faces[(size_t)f * 3 + 1];
    int v2 = faces[(size_t)f * 3 + 2];

    H16 a;
    a.h[0] = __float2half(vnorm[(size_t)v0 * 3 + 0]);
    a.h[1] = __float2half(vnorm[(size_t)v0 * 3 + 1]);
    a.h[2] = __float2half(vnorm[(size_t)v0 * 3 + 2]);
    a.h[3] = __float2half(vnorm[(size_t)v1 * 3 + 0]);
    a.h[4] = __float2half(vnorm[(size_t)v1 * 3 + 1]);
    a.h[5] = __float2half(vnorm[(size_t)v1 * 3 + 2]);
    a.h[6] = __float2half(vnorm[(size_t)v2 * 3 + 0]);
    a.h[7] = __float2half(vnorm[(size_t)v2 * 3 + 1]);
    a.h[8] = __float2half(vnorm[(size_t)v2 * 3 + 2]);
    #pragma unroll
    for (int i = 9; i < 16; ++i) a.h[i] = __half(0.0f);
    attrs[f] = a;
}

// ---------------------------------------------------------------------------
// 2-pixel-per-thread pipelined shader.
//
// Stage L: 6 nontemporal dwordx4 streaming loads per pixel (p2f/dists/zbuf).
// Stage P: pass1 (prob/zinv/zmax/alpha) + branchless k0/k1 select + issue
//          bary + attrs gathers + compute w0/w1. prob[]/zinv[] are NOT kept.
// Stage F: consume gathers, blend, store. Rare >=3-survivor tail (~13% of
//          waves) recomputes pass1 from an L2-warm reload.
//
// Main: L(px0) L(px1) P(px0) P(px1) F(px0) F(px1) — px1's pass1 and px0's
// gather latency overlap; streaming in-flight bytes per wave are doubled.
// ---------------------------------------------------------------------------
struct PixMid {
    float a0, a1, a2, c0, c1, c2;   // bary for slots k0, k1
    H16   g0, g1;                   // attrs for slots k0, k1
    float w0, w1, alpha, zmax;
    int   k0, k1;                   // 8 = none
    int   pix;                      // clamped index (safe for loads)
    bool  more, valid;
};

__device__ __forceinline__ PixMid pass1_px(
    i32x4 F0, i32x4 F1, f32x4 DA, f32x4 DB, f32x4 ZA, f32x4 ZB,
    int pix, bool valid,
    const float* __restrict__ bary, const H16* __restrict__ attrs)
{
    int   faceid[8] = {F0.x, F0.y, F0.z, F0.w, F1.x, F1.y, F1.z, F1.w};
    float dd[8]     = {DA.x, DA.y, DA.z, DA.w, DB.x, DB.y, DB.z, DB.w};
    float zz[8]     = {ZA.x, ZA.y, ZA.z, ZA.w, ZB.x, ZB.y, ZB.z, ZB.w};

    const float inv_sigma = 1.0f / SIGMA_F;
    const float inv_range = 1.0f / (ZFAR_F - ZNEAR_F);
    const float inv_gamma = 1.0f / GAMMA_F;

    float prob[8], zinv[8];
    float zmax = EPS_F, omp = 1.0f;
    #pragma unroll
    for (int k = 0; k < 8; ++k) {
        bool m = faceid[k] >= 0;
        float pm = 1.0f / (1.0f + __expf(dd[k] * inv_sigma));
        pm = m ? pm : 0.0f;
        prob[k] = pm;
        omp *= (1.0f - pm);
        float zi = (ZFAR_F - zz[k]) * inv_range;
        zi = m ? zi : 0.0f;
        zinv[k] = zi;
        zmax = fmaxf(zmax, zi);
    }

    PixMid M;
    M.alpha = 1.0f - omp;
    M.zmax  = zmax;
    M.pix   = pix;
    M.valid = valid;

    // k0 = first non-bg slot (owns zmax, zbuf sorted)
    int k0 = 8, fsel = 0; float zsel = 0.0f, psel = 0.0f;
    #pragma unroll
    for (int k = 7; k >= 0; --k) {
        bool m = faceid[k] >= 0;
        k0 = m ? k : k0;  fsel = m ? faceid[k] : fsel;
        zsel = m ? zinv[k] : zsel;  psel = m ? prob[k] : psel;
    }

    bool ext[8];
    #pragma unroll
    for (int k = 0; k < 8; ++k)
        ext[k] = (faceid[k] >= 0) && ((zinv[k] - zmax) * inv_gamma > CULL_ARG) && (k != k0);

    int k1 = 8, f1sel = 0; float z1 = 0.0f, p1 = 0.0f;
    #pragma unroll
    for (int k = 7; k >= 0; --k) {
        bool e = ext[k];
        k1 = e ? k : k1;  f1sel = e ? faceid[k] : f1sel;
        z1 = e ? zinv[k] : z1;  p1 = e ? prob[k] : p1;
    }
    bool has1 = (k1 < 8);
    M.k0 = k0;  M.k1 = k1;

    bool more = false;
    #pragma unroll
    for (int k = 0; k < 8; ++k) more |= (ext[k] && k != k1);
    M.more = more;

    // Issue gathers for both selected slots together (one round-trip).
    int ko0 = (k0 < 8) ? k0 : 0;
    int ko1 = has1 ? k1 : ko0;
    const float* bp = bary + (size_t)pix * 24;
    M.a0 = bp[ko0 * 3 + 0];  M.a1 = bp[ko0 * 3 + 1];  M.a2 = bp[ko0 * 3 + 2];
    M.c0 = bp[ko1 * 3 + 0];  M.c1 = bp[ko1 * 3 + 1];  M.c2 = bp[ko1 * 3 + 2];
    M.g0 = attrs[fsel];
    M.g1 = attrs[f1sel];

    M.w0 = psel * __expf((zsel - zmax) * inv_gamma);   // zsel==zmax -> ~psel
    float w1 = p1 * __expf((z1 - zmax) * inv_gamma);
    M.w1 = has1 ? w1 : 0.0f;
    return M;
}

__device__ __forceinline__ void finish_px(
    const PixMid& M,
    const int*   __restrict__ pix_to_face,
    const float* __restrict__ bary,
    const float* __restrict__ dists,
    const float* __restrict__ zbuf,
    const H16*   __restrict__ attrs,
    float*       __restrict__ out)
{
    const float inv_sigma = 1.0f / SIGMA_F;
    const float inv_range = 1.0f / (ZFAR_F - ZNEAR_F);
    const float inv_gamma = 1.0f / GAMMA_F;

    float px0 = M.a0 * __half2float(M.g0.h[0]) + M.a1 * __half2float(M.g0.h[3]) + M.a2 * __half2float(M.g0.h[6]);
    float py0 = M.a0 * __half2float(M.g0.h[1]) + M.a1 * __half2float(M.g0.h[4]) + M.a2 * __half2float(M.g0.h[7]);
    float pz0 = M.a0 * __half2float(M.g0.h[2]) + M.a1 * __half2float(M.g0.h[5]) + M.a2 * __half2float(M.g0.h[8]);
    float px1 = M.c0 * __half2float(M.g1.h[0]) + M.c1 * __half2float(M.g1.h[3]) + M.c2 * __half2float(M.g1.h[6]);
    float py1 = M.c0 * __half2float(M.g1.h[1]) + M.c1 * __half2float(M.g1.h[4]) + M.c2 * __half2float(M.g1.h[7]);
    float pz1 = M.c0 * __half2float(M.g1.h[2]) + M.c1 * __half2float(M.g1.h[5]) + M.c2 * __half2float(M.g1.h[8]);

    float wsum = M.w0 + M.w1;
    float cr = M.w0 * px0 + M.w1 * px1;
    float cg = M.w0 * py0 + M.w1 * py1;
    float cb = M.w0 * pz0 + M.w1 * pz1;

    // Rare tail: >=3 survivors. Recompute pass1 from an (L2-warm) reload so
    // the hot path never carries prob[]/zinv[] arrays across phases.
    if (__any((int)M.more)) {
        const i32x4* a4 = reinterpret_cast<const i32x4*>(pix_to_face + (size_t)M.pix * 8);
        i32x4 F0 = a4[0], F1 = a4[1];
        int fid[8] = {F0.x, F0.y, F0.z, F0.w, F1.x, F1.y, F1.z, F1.w};
        const f32x4* d4 = reinterpret_cast<const f32x4*>(dists + (size_t)M.pix * 8);
        f32x4 DA = d4[0], DB = d4[1];
        float dd[8] = {DA.x, DA.y, DA.z, DA.w, DB.x, DB.y, DB.z, DB.w};
        const f32x4* z4 = reinterpret_cast<const f32x4*>(zbuf + (size_t)M.pix * 8);
        f32x4 ZA = z4[0], ZB = z4[1];
        float zz[8] = {ZA.x, ZA.y, ZA.z, ZA.w, ZB.x, ZB.y, ZB.z, ZB.w};
        const float* bp = bary + (size_t)M.pix * 24;

        #pragma unroll
        for (int k = 0; k < 8; ++k) {
            bool m = fid[k] >= 0;
            float pm = 1.0f / (1.0f + __expf(dd[k] * inv_sigma));
            pm = m ? pm : 0.0f;
            float zi = (ZFAR_F - zz[k]) * inv_range;
            zi = m ? zi : 0.0f;
            float arg = (zi - M.zmax) * inv_gamma;
            bool e = m && (arg > CULL_ARG) && (k != M.k0) && (k != M.k1);
            if (e) {
                float b0 = bp[k * 3 + 0], b1 = bp[k * 3 + 1], b2 = bp[k * 3 + 2];
                H16 g = attrs[fid[k]];
                float w = pm * __expf(arg);
                wsum += w;
                cr += w * (b0 * __half2float(g.h[0]) + b1 * __half2float(g.h[3]) + b2 * __half2float(g.h[6]));
                cg += w * (b0 * __half2float(g.h[1]) + b1 * __half2float(g.h[4]) + b2 * __half2float(g.h[7]));
                cb += w * (b0 * __half2float(g.h[2]) + b1 * __half2float(g.h[5]) + b2 * __half2float(g.h[8]));
            }
        }
    }

    float delta = fmaxf(__expf((EPS_F - M.zmax) * inv_gamma), EPS_F);
    float inv_denom = 1.0f / (wsum + delta);

    f32x4 o;
    o.x = (cr + delta) * inv_denom;   // BG_COLOR = (1,1,1)
    o.y = (cg + delta) * inv_denom;
    o.z = (cb + delta) * inv_denom;
    o.w = M.alpha;
    if (M.valid)
        __builtin_nontemporal_store(o, reinterpret_cast<f32x4*>(out) + M.pix);
}

__global__ __launch_bounds__(256, 4) void shade2_kernel(
    const int*   __restrict__ pix_to_face,
    const float* __restrict__ bary,
    const float* __restrict__ dists,
    const float* __restrict__ zbuf,
    const H16*   __restrict__ attrs,
    float*       __restrict__ out,
    int P)
{
    int tid  = threadIdx.x;
    int base = blockIdx.x * 512;

    int pa = base + tid;
    int pb = base + 256 + tid;
    bool va = pa < P, vb = pb < P;
    int qa = va ? pa : 0;
    int qb = vb ? pb : 0;

    // ---- Stage L: issue ALL streaming loads for both pixels ----
    const i32x4* a4 = reinterpret_cast<const i32x4*>(pix_to_face + (size_t)qa * 8);
    i32x4 aF0 = __builtin_nontemporal_load(a4 + 0);
    i32x4 aF1 = __builtin_nontemporal_load(a4 + 1);
    const f32x4* ad4 = reinterpret_cast<const f32x4*>(dists + (size_t)qa * 8);
    f32x4 aDA = __builtin_nontemporal_load(ad4 + 0);
    f32x4 aDB = __builtin_nontemporal_load(ad4 + 1);
    const f32x4* az4 = reinterpret_cast<const f32x4*>(zbuf + (size_t)qa * 8);
    f32x4 aZA = __builtin_nontemporal_load(az4 + 0);
    f32x4 aZB = __builtin_nontemporal_load(az4 + 1);

    const i32x4* b4 = reinterpret_cast<const i32x4*>(pix_to_face + (size_t)qb * 8);
    i32x4 bF0 = __builtin_nontemporal_load(b4 + 0);
    i32x4 bF1 = __builtin_nontemporal_load(b4 + 1);
    const f32x4* bd4 = reinterpret_cast<const f32x4*>(dists + (size_t)qb * 8);
    f32x4 bDA = __builtin_nontemporal_load(bd4 + 0);
    f32x4 bDB = __builtin_nontemporal_load(bd4 + 1);
    const f32x4* bz4 = reinterpret_cast<const f32x4*>(zbuf + (size_t)qb * 8);
    f32x4 bZA = __builtin_nontemporal_load(bz4 + 0);
    f32x4 bZB = __builtin_nontemporal_load(bz4 + 1);

    // ---- Stage P: pass1 + select + gather-issue, pipelined ----
    PixMid M0 = pass1_px(aF0, aF1, aDA, aDB, aZA, aZB, qa, va, bary, attrs);
    PixMid M1 = pass1_px(bF0, bF1, bDA, bDB, bZA, bZB, qb, vb, bary, attrs);

    // ---- Stage F: consume gathers, blend, store ----
    finish_px(M0, pix_to_face, bary, dists, zbuf, attrs, out);
    finish_px(M1, pix_to_face, bary, dists, zbuf, attrs, out);
}

// ---------------------------------------------------------------------------
// Fallback (no workspace): single-pixel fused double gather (round-3 version).
// ---------------------------------------------------------------------------
__global__ __launch_bounds__(256) void normal_shader_fused(
    const int*   __restrict__ pix_to_face,
    const float* __restrict__ bary,
    const float* __restrict__ dists,
    const float* __restrict__ zbuf,
    const int*   __restrict__ faces,
    const float* __restrict__ vnorm,
    float*       __restrict__ out,
    int P)
{
    int pix = blockIdx.x * blockDim.x + threadIdx.x;
    if (pix >= P) return;

    const i32x4* p2f4 = reinterpret_cast<const i32x4*>(pix_to_face + (size_t)pix * 8);
    i32x4 f0 = p2f4[0], f1 = p2f4[1];
    int faceid[8] = {f0.x, f0.y, f0.z, f0.w, f1.x, f1.y, f1.z, f1.w};

    const f32x4* d4 = reinterpret_cast<const f32x4*>(dists + (size_t)pix * 8);
    f32x4 da = d4[0], db = d4[1];
    float dd[8] = {da.x, da.y, da.z, da.w, db.x, db.y, db.z, db.w};

    const f32x4* z4 = reinterpret_cast<const f32x4*>(zbuf + (size_t)pix * 8);
    f32x4 za = z4[0], zb = z4[1];
    float zz[8] = {za.x, za.y, za.z, za.w, zb.x, zb.y, zb.z, zb.w};

    const float inv_sigma = 1.0f / SIGMA_F;
    const float inv_range = 1.0f / (ZFAR_F - ZNEAR_F);
    const float inv_gamma = 1.0f / GAMMA_F;

    float prob[8], zinv[8];
    float zmax = EPS_F, one_minus_prod = 1.0f;

    #pragma unroll
    for (int k = 0; k < 8; ++k) {
        bool m = faceid[k] >= 0;
        float pm = 1.0f / (1.0f + __expf(dd[k] * inv_sigma));
        pm = m ? pm : 0.0f;
        prob[k] = pm;
        one_minus_prod *= (1.0f - pm);
        float zi = (ZFAR_F - zz[k]) * inv_range;
        zinv[k] = m ? zi : 0.0f;
        zmax = fmaxf(zmax, zinv[k]);
    }
    float alpha = 1.0f - one_minus_prod;

    int k0 = 8, fsel = 0; float zsel = 0.0f, psel = 0.0f;
    #pragma unroll
    for (int k = 7; k >= 0; --k) {
        bool m = faceid[k] >= 0;
        k0 = m ? k : k0; fsel = m ? faceid[k] : fsel;
        zsel = m ? zinv[k] : zsel; psel = m ? prob[k] : psel;
    }

    bool ext[8];
    #pragma unroll
    for (int k = 0; k < 8; ++k)
        ext[k] = (faceid[k] >= 0) && ((zinv[k] - zmax) * inv_gamma > CULL_ARG) && (k != k0);

    int k1 = 8, f1sel = 0; float z1 = 0.0f, p1 = 0.0f;
    #pragma unroll
    for (int k = 7; k >= 0; --k) {
        bool e = ext[k];
        k1 = e ? k : k1; f1sel = e ? faceid[k] : f1sel;
        z1 = e ? zinv[k] : z1; p1 = e ? prob[k] : p1;
    }
    bool has1 = (k1 < 8);

    int ko0 = (k0 < 8) ? k0 : 0;
    int ko1 = has1 ? k1 : ko0;
    const float* bp = bary + (size_t)pix * 24;
    float a0 = bp[ko0 * 3 + 0], a1 = bp[ko0 * 3 + 1], a2 = bp[ko0 * 3 + 2];
    float c0 = bp[ko1 * 3 + 0], c1 = bp[ko1 * 3 + 1], c2 = bp[ko1 * 3 + 2];

    int v00 = faces[(size_t)fsel * 3 + 0], v01 = faces[(size_t)fsel * 3 + 1], v02 = faces[(size_t)fsel * 3 + 2];
    int v10 = faces[(size_t)f1sel * 3 + 0], v11 = faces[(size_t)f1sel * 3 + 1], v12 = faces[(size_t)f1sel * 3 + 2];

    float w0 = psel * __expf((zsel - zmax) * inv_gamma);
    float w1 = p1 * __expf((z1 - zmax) * inv_gamma);
    w1 = has1 ? w1 : 0.0f;

    const float* n00 = vnorm + (size_t)v00 * 3;
    const float* n01 = vnorm + (size_t)v01 * 3;
    const float* n02 = vnorm + (size_t)v02 * 3;
    const float* n10 = vnorm + (size_t)v10 * 3;
    const float* n11 = vnorm + (size_t)v11 * 3;
    const float* n12 = vnorm + (size_t)v12 * 3;

    float px0 = a0 * n00[0] + a1 * n01[0] + a2 * n02[0];
    float py0 = a0 * n00[1] + a1 * n01[1] + a2 * n02[1];
    float pz0 = a0 * n00[2] + a1 * n01[2] + a2 * n02[2];
    float px1 = c0 * n10[0] + c1 * n11[0] + c2 * n12[0];
    float py1 = c0 * n10[1] + c1 * n11[1] + c2 * n12[1];
    float pz1 = c0 * n10[2] + c1 * n11[2] + c2 * n12[2];

    float wsum = w0 + w1;
    float cr = w0 * px0 + w1 * px1;
    float cg = w0 * py0 + w1 * py1;
    float cb = w0 * pz0 + w1 * pz1;

    bool more = false;
    #pragma unroll
    for (int k = 0; k < 8; ++k) more |= (ext[k] && k != k1);
    if (__any((int)more)) {
        #pragma unroll
        for (int k = 0; k < 8; ++k) {
            if (ext[k] && k != k1) {
                int fi = faceid[k];
                int u0 = faces[(size_t)fi * 3 + 0];
                int u1 = faces[(size_t)fi * 3 + 1];
                int u2 = faces[(size_t)fi * 3 + 2];
                float b0 = bp[k * 3 + 0], b1 = bp[k * 3 + 1], b2 = bp[k * 3 + 2];
                const float* m0 = vnorm + (size_t)u0 * 3;
                const float* m1 = vnorm + (size_t)u1 * 3;
                const float* m2 = vnorm + (size_t)u2 * 3;
                float w = prob[k] * __expf((zinv[k] - zmax) * inv_gamma);
                wsum += w;
                cr += w * (b0 * m0[0] + b1 * m1[0] + b2 * m2[0]);
                cg += w * (b0 * m0[1] + b1 * m1[1] + b2 * m2[1]);
                cb += w * (b0 * m0[2] + b1 * m1[2] + b2 * m2[2]);
            }
        }
    }

    float delta = fmaxf(__expf((EPS_F - zmax) * inv_gamma), EPS_F);
    float inv_denom = 1.0f / (wsum + delta);
    f32x4 o;
    o.x = (cr + delta) * inv_denom;
    o.y = (cg + delta) * inv_denom;
    o.z = (cb + delta) * inv_denom;
    o.w = alpha;
    reinterpret_cast<f32x4*>(out)[pix] = o;
}

extern "C" void kernel_launch(void* const* d_in, const int* in_sizes, int n_in,
                              void* d_out, int out_size, void* d_ws, size_t ws_size,
                              hipStream_t stream) {
    const int*   pix_to_face = (const int*)  d_in[0];
    const float* bary        = (const float*)d_in[1];
    const float* dists       = (const float*)d_in[2];
    const float* zbuf        = (const float*)d_in[3];
    const int*   faces       = (const int*)  d_in[4];
    const float* vnorm       = (const float*)d_in[5];
    float*       out         = (float*)d_out;

    int P = out_size / 4;       // N*H*W pixels
    int F = in_sizes[4] / 3;    // number of faces
    int block = 256;

    size_t attrs_bytes = (size_t)F * sizeof(H16);
    if (ws_size >= attrs_bytes) {
        H16* attrs = (H16*)d_ws;
        int gridF = (F + block - 1) / block;
        build_face_attrs<<<gridF, block, 0, stream>>>(faces, vnorm, attrs, F);
        int grid2 = (P + 511) / 512;   // 2 pixels per thread
        shade2_kernel<<<grid2, block, 0, stream>>>(
            pix_to_face, bary, dists, zbuf, attrs, out, P);
    } else {
        int gridP = (P + block - 1) / block;
        normal_shader_fused<<<gridP, block, 0, stream>>>(
            pix_to_face, bary, dists, zbuf, faces, vnorm, out, P);
    }
}